// Round 9
// baseline (418.190 us; speedup 1.0000x reference)
//
#include <hip/hip_runtime.h>
#include <cstdint>
#include <cstddef>

#define SEQ 2048
#define DIMM 2048
#define NHEADS 8
#define HDIM 256
#define BATCH 2
#define NROWS 4096      // BATCH*SEQ
#define EDIM 2048       // NHEADS*HDIM
#define NQKV 6144       // 3*EDIM
#define SCALE 0.0625f   // 1/sqrt(256)
#define LOG2E 1.44269504f

typedef __attribute__((ext_vector_type(8))) short bf16x8;   // 8 bf16 in 4 VGPRs
typedef __attribute__((ext_vector_type(4))) float f32x4;
typedef __attribute__((ext_vector_type(16))) float f32x16;
typedef unsigned short u16;
typedef unsigned int u32;

__device__ __forceinline__ u16 f2bf(float f) {
  union { float f; u32 u; } v; v.f = f;
  u32 r = (v.u + 0x7fffu + ((v.u >> 16) & 1u)) >> 16;   // RNE
  return (u16)r;
}
__device__ __forceinline__ float bf2f(u16 b) {
  union { u32 u; float f; } v; v.u = ((u32)b) << 16;
  return v.f;
}
// async global->LDS, 16B per lane. LDS layout must be lane-linear (wave base + lane*16).
__device__ __forceinline__ void gload16(const void* g, void* l) {
  __builtin_amdgcn_global_load_lds(
      (__attribute__((address_space(1))) void*)(void*)g,
      (__attribute__((address_space(3))) void*)l, 16, 0, 0);
}

// ---------------- cast + k-packet transpose ----------------
// xbP[k/8][m], WcatP[k/8][n], WobP[e/8][d]: 16B packets of 8 bf16 along the K dim.
// Packet layout HW-verified conflict-free in the GEMMs (r5/r6: 0 conflicts, passed).
// r8 fix: the packet-READ phase had an 8-way LDS conflict (144B row stride -> bank
// 4m mod 32). Unit u of row r now lives at slot (u+2r)&7 -> read bank 4*((3m+u)%8),
// a permutation (3 coprime 8) => conflict-free. Bit-exact data movement.
__global__ void __launch_bounds__(256) cast_pack(const float* __restrict__ x,
                                                 const float* __restrict__ wq,
                                                 const float* __restrict__ wk,
                                                 const float* __restrict__ wv,
                                                 const float* __restrict__ wo,
                                                 uint4* __restrict__ xbp,
                                                 uint4* __restrict__ wcatp,
                                                 uint4* __restrict__ wobp) {
  const int bid = blockIdx.x;
  const int tid = threadIdx.x;
  __shared__ u16 t[64][72];          // 64x64 bf16 tile, row stride 144B (16B-aligned)
  const int kind = (bid < 2048) ? 0 : ((bid < 5120) ? 1 : 2);  // x / Wqkv / Wo
  const int tt = (kind == 0) ? bid : ((kind == 1) ? bid - 2048 : bid - 5120);
  const int r0 = (tt >> 5) << 6;     // output row (m, n, or d) tile base
  const int c0 = (tt & 31) << 6;     // k tile base
  const float* src;
  int srow;
  if (kind == 0)      { src = x;  srow = r0; }
  else if (kind == 2) { src = wo; srow = r0; }
  else {
    const int sel = r0 >> 11;        // 0..2 -> Wq/Wk/Wv
    src = (sel == 0) ? wq : ((sel == 1) ? wk : wv);
    srow = r0 & 2047;
  }
  // read 64x64 fp32 (coalesced rows), cast, store to LDS at swizzled unit slot
#pragma unroll
  for (int i = 0; i < 4; ++i) {
    const int idx = i * 256 + tid;           // 0..1023
    const int r = idx >> 4, c4 = idx & 15;   // c4: 4-elem group 0..15
    const float4 v = *(const float4*)(src + (long)(srow + r) * 2048 + c0 + c4 * 4);
    ushort4 o;
    o.x = f2bf(v.x); o.y = f2bf(v.y); o.z = f2bf(v.z); o.w = f2bf(v.w);
    const int slot = ((c4 >> 1) + 2 * r) & 7;            // unit (c4>>1) -> slot
    *(ushort4*)&t[r][slot * 8 + (c4 & 1) * 4] = o;
  }
  __syncthreads();
  // write packets: (c0/8 + u) x (r0 + m); contiguous 1KB/wave; conflict-free read
  uint4* dst = (kind == 0) ? xbp : ((kind == 1) ? wcatp : wobp);
  const long R = (kind == 0) ? 4096L : ((kind == 1) ? 6144L : 2048L);
#pragma unroll
  for (int i = 0; i < 2; ++i) {
    const int p = i * 256 + tid;             // 0..511
    const int u = p >> 6, m = p & 63;
    const int slot = (u + 2 * m) & 7;
    const uint4 pk = *(const uint4*)&t[m][slot * 8];
    dst[(long)((c0 >> 3) + u) * R + r0 + m] = pk;
  }
}

// ---------------- GEMM 128x128 2-phase on k-packet layout (QKV projection) -----------
// r6-verified: 0 bank conflicts, MfmaUtil 41.8%. Launched as two half-N dispatches
// (r8-measured neutral; keeps gemm1 instances ~58us in the top-5 sort).
__global__ void __launch_bounds__(256) gemm_pk128(const uint4* __restrict__ AP,
                                                  const uint4* __restrict__ BP,
                                                  u16* __restrict__ Cout,
                                                  int AR, int BR, int N, int K) {
  __shared__ __align__(16) u16 As[8 * 128 * 8];   // 16 KB: packets [u:8][r:128]
  __shared__ __align__(16) u16 Bs[8 * 128 * 8];   // 16 KB
  const int tid = threadIdx.x;
  const int wave = tid >> 6, lane = tid & 63;
  const int l32 = lane & 31, kh = lane >> 5;
  const long bm = (long)blockIdx.x * 128, bn = (long)blockIdx.y * 128;
  const int wm = (wave >> 1) * 64, wn = (wave & 1) * 64;
  f32x16 acc[2][2];
#pragma unroll
  for (int i = 0; i < 2; ++i)
#pragma unroll
    for (int j = 0; j < 2; ++j)
#pragma unroll
      for (int r = 0; r < 16; ++r) acc[i][j][r] = 0.f;

  const int NT = K >> 6;
  for (int t = 0; t < NT; ++t) {
#pragma unroll
    for (int p = 0; p < 4; ++p) {
      const int o = p * 4096 + tid * 16;
      const int u = o >> 11, r = (o >> 4) & 127;
      gload16(AP + (long)(t * 8 + u) * AR + bm + r, (char*)As + o);
      gload16(BP + (long)(t * 8 + u) * BR + bn + r, (char*)Bs + o);
    }
    __syncthreads();
#pragma unroll
    for (int ks = 0; ks < 4; ++ks) {
      bf16x8 af[2], bfr[2];
      const int u = ks * 2 + kh;               // k-packet slot: k = ks*16 + kh*8 + j
#pragma unroll
      for (int t2 = 0; t2 < 2; ++t2) {
        const int ar = wm + t2 * 32 + l32;
        const int br = wn + t2 * 32 + l32;
        af[t2]  = *(const bf16x8*)(As + u * 1024 + ar * 8);   // contiguous, 0-conflict
        bfr[t2] = *(const bf16x8*)(Bs + u * 1024 + br * 8);
      }
#pragma unroll
      for (int i = 0; i < 2; ++i)
#pragma unroll
        for (int j = 0; j < 2; ++j)
          acc[i][j] = __builtin_amdgcn_mfma_f32_32x32x16_bf16(af[i], bfr[j], acc[i][j], 0, 0, 0);
    }
    __syncthreads();
  }
  // epilogue: 32x32 C/D layout col=lane&31, row=(reg&3)+8*(reg>>2)+4*kh
#pragma unroll
  for (int i = 0; i < 2; ++i)
#pragma unroll
    for (int j = 0; j < 2; ++j)
#pragma unroll
      for (int r = 0; r < 16; ++r) {
        const long row = bm + wm + i * 32 + (r & 3) + 8 * (r >> 2) + 4 * kh;
        const long col = bn + wn + j * 32 + l32;
        Cout[row * N + col] = f2bf(acc[i][j][r]);
      }
}

// ---------------- GEMM 128x128 mixed-operand (output projection) ----------------
// A (Ob, row-major) staged with the r4-verified XOR swizzle; B (Wo) packets. fp32 out.
__global__ void __launch_bounds__(256) gemm_mx128(const u16* __restrict__ A,
                                                  const uint4* __restrict__ BP,
                                                  float* __restrict__ Cout,
                                                  int BR, int N, int K) {
  __shared__ __align__(16) u16 As[128 * 64];      // row-major [r:128][k:64]
  __shared__ __align__(16) u16 Bs[8 * 128 * 8];   // packets [u:8][r:128]
  const int tid = threadIdx.x;
  const int wave = tid >> 6, lane = tid & 63;
  const int l32 = lane & 31, kh = lane >> 5;
  const long bm = (long)blockIdx.x * 128, bn = (long)blockIdx.y * 128;
  const int wm = (wave >> 1) * 64, wn = (wave & 1) * 64;
  f32x16 acc[2][2];
#pragma unroll
  for (int i = 0; i < 2; ++i)
#pragma unroll
    for (int j = 0; j < 2; ++j)
#pragma unroll
      for (int r = 0; r < 16; ++r) acc[i][j][r] = 0.f;

  const int NT = K >> 6;
  for (int t = 0; t < NT; ++t) {
    const int k0 = t * 64;
#pragma unroll
    for (int p = 0; p < 4; ++p) {
      const int o = p * 4096 + tid * 16;
      // A: row-major swizzled stage (gemm_bt pattern, r4-verified)
      const int row = o >> 7;
      const int cg = ((o >> 4) & 7) ^ (row & 7);
      gload16(A + (bm + row) * (long)K + k0 + cg * 8, (char*)As + o);
      // B: packet stage (gemm_pk128 pattern, r6-verified)
      const int u = o >> 11, r = (o >> 4) & 127;
      gload16(BP + (long)(t * 8 + u) * BR + bn + r, (char*)Bs + o);
    }
    __syncthreads();
#pragma unroll
    for (int ks = 0; ks < 4; ++ks) {
      bf16x8 af[2], bfr[2];
      const int u = ks * 2 + kh;
#pragma unroll
      for (int t2 = 0; t2 < 2; ++t2) {
        const int ar = wm + t2 * 32 + l32;
        const int br = wn + t2 * 32 + l32;
        af[t2]  = *(const bf16x8*)(As + ar * 64 + ((u ^ (ar & 7)) * 8));  // swizzled
        bfr[t2] = *(const bf16x8*)(Bs + u * 1024 + br * 8);               // packet
      }
#pragma unroll
      for (int i = 0; i < 2; ++i)
#pragma unroll
        for (int j = 0; j < 2; ++j)
          acc[i][j] = __builtin_amdgcn_mfma_f32_32x32x16_bf16(af[i], bfr[j], acc[i][j], 0, 0, 0);
    }
    __syncthreads();
  }
#pragma unroll
  for (int i = 0; i < 2; ++i)
#pragma unroll
    for (int j = 0; j < 2; ++j)
#pragma unroll
      for (int r = 0; r < 16; ++r) {
        const long row = bm + wm + i * 32 + (r & 3) + 8 * (r >> 2) + 4 * kh;
        const long col = bn + wn + j * 32 + l32;
        Cout[row * N + col] = acc[i][j][r];
      }
}

// ---------------- fused RMSnorm+RoPE (q/k) + V transpose, one launch ----------------
// r8 change: norm arm vectorized (G13) — dword loads/stores (2 elems/access) with
// lane-local RoPE pairing {2l,2l+1}<->{2l+128,2l+129}. Per-element math identical to
// the verified scalar version (same freq formula at same element index); only the
// rms-sum reduction order changes (ulp-level). 4x fewer memory instructions.
__global__ void __launch_bounds__(256) norm_rope_tv(u16* __restrict__ qkv,
                                                    const int* __restrict__ pos_ids,
                                                    const float* __restrict__ qw,
                                                    const float* __restrict__ kw,
                                                    u16* __restrict__ vt) {
  __shared__ u16 tile[64][73];
  if (blockIdx.x < 16384) {
    const int job = blockIdx.x * 4 + (threadIdx.x >> 6);
    const int lane = threadIdx.x & 63;
    const int which = job >> 15;       // 0 = q, 1 = k
    const int j2 = job & 32767;
    const int r = j2 >> 3;             // row 0..4095 (b*S+s)
    const int h = j2 & 7;
    const int s = r & (SEQ - 1);
    const int pos = pos_ids[s];
    const float* w = which ? kw : qw;
    u16* p = qkv + (long)r * NQKV + which * EDIM + h * HDIM;

    // lane covers elems {2l, 2l+1} (lo half, d<128) and {2l+128, 2l+129} (hi half)
    const u32 ua = *(const u32*)(p + 2 * lane);
    const u32 ub = *(const u32*)(p + 128 + 2 * lane);
    float xa0 = bf2f((u16)ua), xa1 = bf2f((u16)(ua >> 16));
    float xb0 = bf2f((u16)ub), xb1 = bf2f((u16)(ub >> 16));
    float ss = xa0 * xa0 + xa1 * xa1 + xb0 * xb0 + xb1 * xb1;
#pragma unroll
    for (int off = 1; off < 64; off <<= 1) ss += __shfl_xor(ss, off);
    const float rinv = rsqrtf(ss * (1.0f / HDIM) + 1e-6f);
    const float2 wa = *(const float2*)(w + 2 * lane);
    const float2 wb = *(const float2*)(w + 128 + 2 * lane);
    xa0 *= rinv * wa.x; xa1 *= rinv * wa.y;
    xb0 *= rinv * wb.x; xb1 *= rinv * wb.y;
    const float L2TEN4 = 13.287712379549449f;  // log2(10000)
    const float f0 = exp2f(-(2.0f * (2 * lane) / HDIM) * L2TEN4);
    const float f1 = exp2f(-(2.0f * (2 * lane + 1) / HDIM) * L2TEN4);
    const float a0 = pos * f0, a1 = pos * f1;
    float s0, c0, s1, c1;
    __sincosf(a0, &s0, &c0);
    __sincosf(a1, &s1, &c1);
    const float lo0 = xa0 * c0 - xb0 * s0, lo1 = xa1 * c1 - xb1 * s1;
    const float hi0 = xb0 * c0 + xa0 * s0, hi1 = xb1 * c1 + xa1 * s1;
    *(u32*)(p + 2 * lane)       = (u32)f2bf(lo0) | ((u32)f2bf(lo1) << 16);
    *(u32*)(p + 128 + 2 * lane) = (u32)f2bf(hi0) | ((u32)f2bf(hi1) << 16);
  } else {
    const int t = blockIdx.x - 16384;
    const int tid = threadIdx.x;
    const int st = (t & 31) * 64;
    const int dt = ((t >> 5) & 3) * 64;
    const int bh = t >> 7;
    const int b = bh >> 3, h = bh & 7;
    const u16* src = qkv + (long)(b * SEQ + st) * NQKV + 2 * EDIM + h * HDIM + dt;
#pragma unroll
    for (int p = 0; p < 2; ++p) {
      const int idx = p * 2048 + tid * 8;
      const int sr = idx >> 6, dc = idx & 63;
      const uint4 v = *(const uint4*)(src + (long)sr * NQKV + dc);
      const u16* pv = (const u16*)&v;
#pragma unroll
      for (int e = 0; e < 8; ++e) tile[sr][dc + e] = pv[e];
    }
    __syncthreads();
    u16* dst = vt + ((long)bh * HDIM + dt) * SEQ + st;
#pragma unroll
    for (int p = 0; p < 2; ++p) {
      const int idx = p * 2048 + tid * 8;
      const int dr = idx >> 6, sc = idx & 63;
      u16 tmp[8];
#pragma unroll
      for (int e = 0; e < 8; ++e) tmp[e] = tile[sc + e][dr];
      *(uint4*)(dst + (long)dr * SEQ + sc) = *(const uint4*)tmp;
    }
  }
}

// ---------------- flash attention v3: 2-barrier loop + T5 setprio --------------------
// r8 change: grid split along bh (bh0 param, grid.x=8, two launches) so each dispatch
// is ~33us — pushes flash below the gemm1 halves in the top-5 sort (attribution).
__global__ void __launch_bounds__(256) flash_attn(const u16* __restrict__ qkv,
                                                  const u16* __restrict__ vt,
                                                  u16* __restrict__ opart,
                                                  float* __restrict__ lpart,
                                                  u16* __restrict__ ob,
                                                  int bh0) {
  const int bh = bh0 + blockIdx.x, b = bh >> 3, h = bh & 7;
  const int qt = 31 - (int)blockIdx.y;
  const int kc = blockIdx.z;
  if (kc && qt < 16) return;
  const int kt0 = kc * 16;
  const int kt_end = (qt < kt0 + 15) ? qt : (kt0 + 15);

  __shared__ __align__(16) u16 Ks[64 * 256];
  __shared__ __align__(16) u16 Vs[256 * 64];
  __shared__ __align__(16) u16 Pb[4 * 16 * 64];
  const int tid = threadIdx.x;
  const int wave = tid >> 6, lane = tid & 63;
  const int quad = lane >> 4, l16 = lane & 15;
  const long qbase = (long)(b * SEQ + qt * 64) * NQKV + h * HDIM;
  const long kbase = (long)(b * SEQ) * NQKV + EDIM + h * HDIM;
  const long vbase = (long)bh * HDIM * SEQ;

#pragma unroll
  for (int p = 0; p < 8; ++p) {
    const int o = p * 4096 + tid * 16;
    const int row = o >> 9;
    const int cg = ((o >> 4) & 31) ^ (row & 7);
    gload16(qkv + qbase + (long)row * NQKV + cg * 8, (char*)Ks + o);
  }
  __syncthreads();
  bf16x8 qf[8];
  {
    const int qr = wave * 16 + l16;
#pragma unroll
    for (int ks = 0; ks < 8; ++ks) {
      const int u = ks * 4 + quad;
      qf[ks] = *(const bf16x8*)(Ks + qr * 256 + (u ^ (qr & 7)) * 8);
    }
  }
  __syncthreads();

#pragma unroll
  for (int p = 0; p < 8; ++p) {
    const int o = p * 4096 + tid * 16;
    const int row = o >> 9;
    const int cg = ((o >> 4) & 31) ^ (row & 7);
    gload16(qkv + kbase + (long)(kt0 * 64 + row) * NQKV + cg * 8, (char*)Ks + o);
  }

  const f32x4 fz = {0.f, 0.f, 0.f, 0.f};
  f32x4 O[16];
#pragma unroll
  for (int t = 0; t < 16; ++t) O[t] = fz;
  float lacc[4] = {0.f, 0.f, 0.f, 0.f};
  const float C1 = SCALE * LOG2E;
  const float C2 = 16.0f * LOG2E;

  for (int kt = kt0; kt <= kt_end; ++kt) {
    __syncthreads();
#pragma unroll
    for (int p = 0; p < 8; ++p) {
      const int o = p * 4096 + tid * 16;
      const int row = o >> 7;
      const int cg = ((o >> 4) & 7) ^ (row & 7);
      gload16(vt + vbase + (long)row * SEQ + kt * 64 + cg * 8, (char*)Vs + o);
    }
    f32x4 S[4];
#pragma unroll
    for (int nt = 0; nt < 4; ++nt) S[nt] = fz;
    __builtin_amdgcn_s_setprio(1);
#pragma unroll
    for (int nt = 0; nt < 4; ++nt) {
      const int kr = nt * 16 + l16;
#pragma unroll
      for (int ks = 0; ks < 8; ++ks) {
        const int u = ks * 4 + quad;
        const bf16x8 kf = *(const bf16x8*)(Ks + kr * 256 + (u ^ (kr & 7)) * 8);
        S[nt] = __builtin_amdgcn_mfma_f32_16x16x32_bf16(qf[ks], kf, S[nt], 0, 0, 0);
      }
    }
    __builtin_amdgcn_s_setprio(0);
    u16* Pw = Pb + wave * (16 * 64);
    if (kt == qt) {
      const int qg0 = qt * 64 + wave * 16 + quad * 4;
      const int kg0 = kt * 64 + l16;
#pragma unroll
      for (int nt = 0; nt < 4; ++nt) {
        const int kg = kg0 + nt * 16;
#pragma unroll
        for (int r = 0; r < 4; ++r) {
          float p = exp2f(S[nt][r] * C1 - C2);
          p = (kg <= qg0 + r) ? p : 0.f;
          lacc[r] += p;
          const int qrow = quad * 4 + r;
          const int col = nt * 16 + l16;
          Pw[qrow * 64 + (((col >> 3) ^ (qrow & 7)) * 8) + (col & 7)] = f2bf(p);
        }
      }
    } else {
#pragma unroll
      for (int nt = 0; nt < 4; ++nt) {
#pragma unroll
        for (int r = 0; r < 4; ++r) {
          const float p = exp2f(S[nt][r] * C1 - C2);
          lacc[r] += p;
          const int qrow = quad * 4 + r;
          const int col = nt * 16 + l16;
          Pw[qrow * 64 + (((col >> 3) ^ (qrow & 7)) * 8) + (col & 7)] = f2bf(p);
        }
      }
    }
    __syncthreads();
    if (kt < kt_end) {
#pragma unroll
      for (int p = 0; p < 8; ++p) {
        const int o = p * 4096 + tid * 16;
        const int row = o >> 9;
        const int cg = ((o >> 4) & 31) ^ (row & 7);
        gload16(qkv + kbase + (long)((kt + 1) * 64 + row) * NQKV + cg * 8, (char*)Ks + o);
      }
    }
    bf16x8 pf[2];
#pragma unroll
    for (int ks = 0; ks < 2; ++ks) {
      const int u = ks * 4 + quad;
      pf[ks] = *(const bf16x8*)(Pw + l16 * 64 + (u ^ (l16 & 7)) * 8);
    }
    __builtin_amdgcn_s_setprio(1);
#pragma unroll
    for (int nt = 0; nt < 16; ++nt) {
      const int vr = nt * 16 + l16;
#pragma unroll
      for (int ks = 0; ks < 2; ++ks) {
        const int u = ks * 4 + quad;
        const bf16x8 vf = *(const bf16x8*)(Vs + vr * 64 + (u ^ (vr & 7)) * 8);
        O[nt] = __builtin_amdgcn_mfma_f32_16x16x32_bf16(pf[ks], vf, O[nt], 0, 0, 0);
      }
    }
    __builtin_amdgcn_s_setprio(0);
  }
#pragma unroll
  for (int off = 1; off < 16; off <<= 1)
#pragma unroll
    for (int r = 0; r < 4; ++r) lacc[r] += __shfl_xor(lacc[r], off);

  if (qt < 16) {
    const float rv[4] = {1.0f / lacc[0], 1.0f / lacc[1], 1.0f / lacc[2], 1.0f / lacc[3]};
#pragma unroll
    for (int nt = 0; nt < 16; ++nt) {
      const int col = nt * 16 + l16;
#pragma unroll
      for (int r = 0; r < 4; ++r) {
        const int qrow = wave * 16 + quad * 4 + r;
        ob[((long)(b * SEQ + qt * 64 + qrow)) * EDIM + h * HDIM + col] =
            f2bf(O[nt][r] * rv[r]);
      }
    }
  } else {
    const long pbase = ((long)(bh * 32 + qt) * 2 + kc) * (64 * 256);
#pragma unroll
    for (int nt = 0; nt < 16; ++nt) {
      const int col = nt * 16 + l16;
#pragma unroll
      for (int r = 0; r < 4; ++r) {
        const int qrow = wave * 16 + quad * 4 + r;
        opart[pbase + (long)qrow * 256 + col] = f2bf(O[nt][r]);
      }
    }
    if (l16 == 0) {
      const long lbase = ((long)(bh * 32 + qt) * 2 + kc) * 64;
#pragma unroll
      for (int r = 0; r < 4; ++r)
        lpart[lbase + wave * 16 + quad * 4 + r] = lacc[r];
    }
  }
}

// ---------------- combine split-K partials (qt>=16 only) ----------------
__global__ void __launch_bounds__(256) fa_combine(const u16* __restrict__ opart,
                                                  const float* __restrict__ lpart,
                                                  u16* __restrict__ ob) {
  const int bh = blockIdx.x, qt = 16 + blockIdx.y;
  const int b = bh >> 3, h = bh & 7;
  const long p0 = ((long)(bh * 32 + qt) * 2) * (64 * 256);
  const long l0 = ((long)(bh * 32 + qt) * 2) * 64;
  __shared__ float rl[64];
  if (threadIdx.x < 64) {
    const float l = lpart[l0 + threadIdx.x] + lpart[l0 + 64 + threadIdx.x];
    rl[threadIdx.x] = 1.0f / l;
  }
  __syncthreads();
#pragma unroll
  for (int i = 0; i < 8; ++i) {
    const int e = i * 2048 + threadIdx.x * 8;
    const int row = e >> 8, d = e & 255;
    const u16* a = opart + p0 + e;
    const u16* c = a + 64 * 256;
    float v[8];
#pragma unroll
    for (int j = 0; j < 8; ++j) v[j] = bf2f(a[j]) + bf2f(c[j]);
    const float inv = rl[row];
    u16 o[8];
#pragma unroll
    for (int j = 0; j < 8; ++j) o[j] = f2bf(v[j] * inv);
    *(uint4*)(ob + ((long)(b * SEQ + qt * 64 + row)) * EDIM + h * HDIM + d) =
        *(const uint4*)o;
  }
}

// ---------------- launch ----------------
extern "C" void kernel_launch(void* const* d_in, const int* in_sizes, int n_in,
                              void* d_out, int out_size, void* d_ws, size_t ws_size,
                              hipStream_t stream) {
  const float* x  = (const float*)d_in[0];
  const int* pos  = (const int*)d_in[1];
  const float* Wq = (const float*)d_in[2];
  const float* Wk = (const float*)d_in[3];
  const float* Wv = (const float*)d_in[4];
  const float* Wo = (const float*)d_in[5];
  const float* qw = (const float*)d_in[6];
  const float* kw = (const float*)d_in[7];

  char* ws = (char*)d_ws;
  uint4* xbP   = (uint4*)(ws);               // 16 MiB  x packets [256][4096]  [dead after GEMM1]
  uint4* WcatP = (uint4*)(ws + 16777216L);   // 24 MiB  W packets [256][6144]  [dead after GEMM1]
  uint4* WobP  = (uint4*)(ws + 41943040L);   //  8 MiB  Wo packets [256][2048]
  u16* QKVb = (u16*)(ws + 50331648L);        // 48 MiB  qkv bf16 (4096x6144)
  u16* Vt   = (u16*)(ws + 100663296L);       // 16 MiB  V^T bf16 (16x256x2048)
  u16* Ob   = (u16*)(ws + 117440512L);       // 16 MiB  attn out bf16 (4096x2048)
  u16*   Opart = (u16*)(ws);                 // 32 MiB  overlay (dead xbP/WcatP region)
  float* Lpart = (float*)(ws + 33554432L);   // 256 KiB

  cast_pack<<<6144, 256, 0, stream>>>(x, Wq, Wk, Wv, Wo, xbP, WcatP, WobP);

  // QKV projection: two half-N dispatches (r8-measured config)
  gemm_pk128<<<dim3(32, 24), 256, 0, stream>>>(xbP, WcatP, QKVb, 4096, 6144, NQKV, DIMM);
  gemm_pk128<<<dim3(32, 24), 256, 0, stream>>>(xbP, WcatP + 3072, QKVb + 3072,
                                               4096, 6144, NQKV, DIMM);
  norm_rope_tv<<<18432, 256, 0, stream>>>(QKVb, pos, qw, kw, Vt);
  // flash attention: two bh-halves (~33us each)
  flash_attn<<<dim3(8, 32, 2), 256, 0, stream>>>(QKVb, Vt, Opart, Lpart, Ob, 0);
  flash_attn<<<dim3(8, 32, 2), 256, 0, stream>>>(QKVb, Vt, Opart, Lpart, Ob, 8);
  fa_combine<<<dim3(16, 16), 256, 0, stream>>>(Opart, Lpart, Ob);
  // output projection: mixed-operand kernel (A row-major swizzled, B packets), fp32 out
  gemm_mx128<<<dim3(32, 16), 256, 0, stream>>>(Ob, WobP, (float*)d_out, 2048, DIMM, EDIM);
}

// Round 10
// 371.243 us; speedup vs baseline: 1.1265x; 1.1265x over previous
//
#include <hip/hip_runtime.h>
#include <cstdint>
#include <cstddef>

#define SEQ 2048
#define DIMM 2048
#define NHEADS 8
#define HDIM 256
#define BATCH 2
#define NROWS 4096      // BATCH*SEQ
#define EDIM 2048       // NHEADS*HDIM
#define NQKV 6144       // 3*EDIM
#define SCALE 0.0625f   // 1/sqrt(256)
#define LOG2E 1.44269504f

typedef __attribute__((ext_vector_type(8))) short bf16x8;   // 8 bf16 in 4 VGPRs
typedef __attribute__((ext_vector_type(4))) float f32x4;
typedef __attribute__((ext_vector_type(16))) float f32x16;
typedef unsigned short u16;
typedef unsigned int u32;

__device__ __forceinline__ u16 f2bf(float f) {
  union { float f; u32 u; } v; v.f = f;
  u32 r = (v.u + 0x7fffu + ((v.u >> 16) & 1u)) >> 16;   // RNE
  return (u16)r;
}
__device__ __forceinline__ float bf2f(u16 b) {
  union { u32 u; float f; } v; v.u = ((u32)b) << 16;
  return v.f;
}
// async global->LDS, 16B per lane. LDS layout must be lane-linear (wave base + lane*16).
__device__ __forceinline__ void gload16(const void* g, void* l) {
  __builtin_amdgcn_global_load_lds(
      (__attribute__((address_space(1))) void*)(void*)g,
      (__attribute__((address_space(3))) void*)l, 16, 0, 0);
}

// ---------------- cast + k-packet transpose (r9-verified incl. slot swizzle) ---------
// xbP[k/8][m], WcatP[k/8][n], WobP[e/8][d]: 16B packets of 8 bf16 along the K dim.
// Unit u of row r lives at LDS slot (u+2r)&7 -> conflict-free packet read (r9 passed).
__global__ void __launch_bounds__(256) cast_pack(const float* __restrict__ x,
                                                 const float* __restrict__ wq,
                                                 const float* __restrict__ wk,
                                                 const float* __restrict__ wv,
                                                 const float* __restrict__ wo,
                                                 uint4* __restrict__ xbp,
                                                 uint4* __restrict__ wcatp,
                                                 uint4* __restrict__ wobp) {
  const int bid = blockIdx.x;
  const int tid = threadIdx.x;
  __shared__ u16 t[64][72];          // 64x64 bf16 tile, row stride 144B (16B-aligned)
  const int kind = (bid < 2048) ? 0 : ((bid < 5120) ? 1 : 2);  // x / Wqkv / Wo
  const int tt = (kind == 0) ? bid : ((kind == 1) ? bid - 2048 : bid - 5120);
  const int r0 = (tt >> 5) << 6;     // output row (m, n, or d) tile base
  const int c0 = (tt & 31) << 6;     // k tile base
  const float* src;
  int srow;
  if (kind == 0)      { src = x;  srow = r0; }
  else if (kind == 2) { src = wo; srow = r0; }
  else {
    const int sel = r0 >> 11;        // 0..2 -> Wq/Wk/Wv
    src = (sel == 0) ? wq : ((sel == 1) ? wk : wv);
    srow = r0 & 2047;
  }
#pragma unroll
  for (int i = 0; i < 4; ++i) {
    const int idx = i * 256 + tid;           // 0..1023
    const int r = idx >> 4, c4 = idx & 15;   // c4: 4-elem group 0..15
    const float4 v = *(const float4*)(src + (long)(srow + r) * 2048 + c0 + c4 * 4);
    ushort4 o;
    o.x = f2bf(v.x); o.y = f2bf(v.y); o.z = f2bf(v.z); o.w = f2bf(v.w);
    const int slot = ((c4 >> 1) + 2 * r) & 7;            // unit (c4>>1) -> slot
    *(ushort4*)&t[r][slot * 8 + (c4 & 1) * 4] = o;
  }
  __syncthreads();
  uint4* dst = (kind == 0) ? xbp : ((kind == 1) ? wcatp : wobp);
  const long R = (kind == 0) ? 4096L : ((kind == 1) ? 6144L : 2048L);
#pragma unroll
  for (int i = 0; i < 2; ++i) {
    const int p = i * 256 + tid;             // 0..511
    const int u = p >> 6, m = p & 63;
    const int slot = (u + 2 * m) & 7;
    const uint4 pk = *(const uint4*)&t[m][slot * 8];
    dst[(long)((c0 >> 3) + u) * R + r0 + m] = pk;
  }
}

// ---------------- GEMM 128x128 2-phase on k-packet layout (QKV projection) -----------
// r6-verified single dispatch: 0 bank conflicts, MfmaUtil 41.8%, 112.5us.
// (r9's two-half split cost ~5us — reverted.)
__global__ void __launch_bounds__(256) gemm_pk128(const uint4* __restrict__ AP,
                                                  const uint4* __restrict__ BP,
                                                  u16* __restrict__ Cout,
                                                  int AR, int BR, int N, int K) {
  __shared__ __align__(16) u16 As[8 * 128 * 8];   // 16 KB: packets [u:8][r:128]
  __shared__ __align__(16) u16 Bs[8 * 128 * 8];   // 16 KB
  const int tid = threadIdx.x;
  const int wave = tid >> 6, lane = tid & 63;
  const int l32 = lane & 31, kh = lane >> 5;
  const long bm = (long)blockIdx.x * 128, bn = (long)blockIdx.y * 128;
  const int wm = (wave >> 1) * 64, wn = (wave & 1) * 64;
  f32x16 acc[2][2];
#pragma unroll
  for (int i = 0; i < 2; ++i)
#pragma unroll
    for (int j = 0; j < 2; ++j)
#pragma unroll
      for (int r = 0; r < 16; ++r) acc[i][j][r] = 0.f;

  const int NT = K >> 6;
  for (int t = 0; t < NT; ++t) {
#pragma unroll
    for (int p = 0; p < 4; ++p) {
      const int o = p * 4096 + tid * 16;
      const int u = o >> 11, r = (o >> 4) & 127;
      gload16(AP + (long)(t * 8 + u) * AR + bm + r, (char*)As + o);
      gload16(BP + (long)(t * 8 + u) * BR + bn + r, (char*)Bs + o);
    }
    __syncthreads();
#pragma unroll
    for (int ks = 0; ks < 4; ++ks) {
      bf16x8 af[2], bfr[2];
      const int u = ks * 2 + kh;               // k-packet slot: k = ks*16 + kh*8 + j
#pragma unroll
      for (int t2 = 0; t2 < 2; ++t2) {
        const int ar = wm + t2 * 32 + l32;
        const int br = wn + t2 * 32 + l32;
        af[t2]  = *(const bf16x8*)(As + u * 1024 + ar * 8);   // contiguous, 0-conflict
        bfr[t2] = *(const bf16x8*)(Bs + u * 1024 + br * 8);
      }
#pragma unroll
      for (int i = 0; i < 2; ++i)
#pragma unroll
        for (int j = 0; j < 2; ++j)
          acc[i][j] = __builtin_amdgcn_mfma_f32_32x32x16_bf16(af[i], bfr[j], acc[i][j], 0, 0, 0);
    }
    __syncthreads();
  }
  // epilogue: 32x32 C/D layout col=lane&31, row=(reg&3)+8*(reg>>2)+4*kh
#pragma unroll
  for (int i = 0; i < 2; ++i)
#pragma unroll
    for (int j = 0; j < 2; ++j)
#pragma unroll
      for (int r = 0; r < 16; ++r) {
        const long row = bm + wm + i * 32 + (r & 3) + 8 * (r >> 2) + 4 * kh;
        const long col = bn + wn + j * 32 + l32;
        Cout[row * N + col] = f2bf(acc[i][j][r]);
      }
}

// ---------------- GEMM 128x128 mixed-operand (output projection) ----------------
// A (Ob, row-major) staged with the r4-verified XOR swizzle; B (Wo) packets. fp32 out.
__global__ void __launch_bounds__(256) gemm_mx128(const u16* __restrict__ A,
                                                  const uint4* __restrict__ BP,
                                                  float* __restrict__ Cout,
                                                  int BR, int N, int K) {
  __shared__ __align__(16) u16 As[128 * 64];      // row-major [r:128][k:64]
  __shared__ __align__(16) u16 Bs[8 * 128 * 8];   // packets [u:8][r:128]
  const int tid = threadIdx.x;
  const int wave = tid >> 6, lane = tid & 63;
  const int l32 = lane & 31, kh = lane >> 5;
  const long bm = (long)blockIdx.x * 128, bn = (long)blockIdx.y * 128;
  const int wm = (wave >> 1) * 64, wn = (wave & 1) * 64;
  f32x16 acc[2][2];
#pragma unroll
  for (int i = 0; i < 2; ++i)
#pragma unroll
    for (int j = 0; j < 2; ++j)
#pragma unroll
      for (int r = 0; r < 16; ++r) acc[i][j][r] = 0.f;

  const int NT = K >> 6;
  for (int t = 0; t < NT; ++t) {
    const int k0 = t * 64;
#pragma unroll
    for (int p = 0; p < 4; ++p) {
      const int o = p * 4096 + tid * 16;
      const int row = o >> 7;
      const int cg = ((o >> 4) & 7) ^ (row & 7);
      gload16(A + (bm + row) * (long)K + k0 + cg * 8, (char*)As + o);
      const int u = o >> 11, r = (o >> 4) & 127;
      gload16(BP + (long)(t * 8 + u) * BR + bn + r, (char*)Bs + o);
    }
    __syncthreads();
#pragma unroll
    for (int ks = 0; ks < 4; ++ks) {
      bf16x8 af[2], bfr[2];
      const int u = ks * 2 + kh;
#pragma unroll
      for (int t2 = 0; t2 < 2; ++t2) {
        const int ar = wm + t2 * 32 + l32;
        const int br = wn + t2 * 32 + l32;
        af[t2]  = *(const bf16x8*)(As + ar * 64 + ((u ^ (ar & 7)) * 8));  // swizzled
        bfr[t2] = *(const bf16x8*)(Bs + u * 1024 + br * 8);               // packet
      }
#pragma unroll
      for (int i = 0; i < 2; ++i)
#pragma unroll
        for (int j = 0; j < 2; ++j)
          acc[i][j] = __builtin_amdgcn_mfma_f32_32x32x16_bf16(af[i], bfr[j], acc[i][j], 0, 0, 0);
    }
    __syncthreads();
  }
#pragma unroll
  for (int i = 0; i < 2; ++i)
#pragma unroll
    for (int j = 0; j < 2; ++j)
#pragma unroll
      for (int r = 0; r < 16; ++r) {
        const long row = bm + wm + i * 32 + (r & 3) + 8 * (r >> 2) + 4 * kh;
        const long col = bn + wn + j * 32 + l32;
        Cout[row * N + col] = acc[i][j][r];
      }
}

// ---------------- RoPE table: tab[s][lane] = {c0,s0,c1,s1} for d={2l,2l+1} ----------
// Angles depend only on (s, lane) but were recomputed 16x (8 heads x q/k) per position
// in the norm kernel (2 exp2 + 2 sincos per lane per job). Build once: 131K entries.
// Expressions copied VERBATIM from the r9 norm kernel -> bit-identical results.
__global__ void __launch_bounds__(256) rope_table(const int* __restrict__ pos_ids,
                                                  float4* __restrict__ tab) {
  const int t = blockIdx.x * 256 + threadIdx.x;   // 0..131071
  const int s = t >> 6, l = t & 63;
  const int pos = pos_ids[s];
  const float L2TEN4 = 13.287712379549449f;  // log2(10000)
  const float f0 = exp2f(-(2.0f * (2 * l) / HDIM) * L2TEN4);
  const float f1 = exp2f(-(2.0f * (2 * l + 1) / HDIM) * L2TEN4);
  float s0, c0, s1, c1;
  __sincosf(pos * f0, &s0, &c0);
  __sincosf(pos * f1, &s1, &c1);
  tab[t] = make_float4(c0, s0, c1, s1);
}

// ---------------- fused RMSnorm+RoPE (q/k) + V transpose, one launch ----------------
// r9-verified vectorized norm arm; r10: trig via rope_table (one 16B L2-hit load
// replaces 2 exp2 + 2 sincos per lane per job).
__global__ void __launch_bounds__(256) norm_rope_tv(u16* __restrict__ qkv,
                                                    const float4* __restrict__ tab,
                                                    const float* __restrict__ qw,
                                                    const float* __restrict__ kw,
                                                    u16* __restrict__ vt) {
  __shared__ u16 tile[64][73];
  if (blockIdx.x < 16384) {
    const int job = blockIdx.x * 4 + (threadIdx.x >> 6);
    const int lane = threadIdx.x & 63;
    const int which = job >> 15;       // 0 = q, 1 = k
    const int j2 = job & 32767;
    const int r = j2 >> 3;             // row 0..4095 (b*S+s)
    const int h = j2 & 7;
    const int s = r & (SEQ - 1);
    const float* w = which ? kw : qw;
    u16* p = qkv + (long)r * NQKV + which * EDIM + h * HDIM;

    // lane covers elems {2l, 2l+1} (lo half, d<128) and {2l+128, 2l+129} (hi half)
    const u32 ua = *(const u32*)(p + 2 * lane);
    const u32 ub = *(const u32*)(p + 128 + 2 * lane);
    float xa0 = bf2f((u16)ua), xa1 = bf2f((u16)(ua >> 16));
    float xb0 = bf2f((u16)ub), xb1 = bf2f((u16)(ub >> 16));
    float ss = xa0 * xa0 + xa1 * xa1 + xb0 * xb0 + xb1 * xb1;
#pragma unroll
    for (int off = 1; off < 64; off <<= 1) ss += __shfl_xor(ss, off);
    const float rinv = rsqrtf(ss * (1.0f / HDIM) + 1e-6f);
    const float2 wa = *(const float2*)(w + 2 * lane);
    const float2 wb = *(const float2*)(w + 128 + 2 * lane);
    xa0 *= rinv * wa.x; xa1 *= rinv * wa.y;
    xb0 *= rinv * wb.x; xb1 *= rinv * wb.y;
    const float4 cs = tab[(long)s * 64 + lane];   // {c0,s0,c1,s1}
    const float lo0 = xa0 * cs.x - xb0 * cs.y, lo1 = xa1 * cs.z - xb1 * cs.w;
    const float hi0 = xb0 * cs.x + xa0 * cs.y, hi1 = xb1 * cs.z + xa1 * cs.w;
    *(u32*)(p + 2 * lane)       = (u32)f2bf(lo0) | ((u32)f2bf(lo1) << 16);
    *(u32*)(p + 128 + 2 * lane) = (u32)f2bf(hi0) | ((u32)f2bf(hi1) << 16);
  } else {
    const int t = blockIdx.x - 16384;
    const int tid = threadIdx.x;
    const int st = (t & 31) * 64;
    const int dt = ((t >> 5) & 3) * 64;
    const int bh = t >> 7;
    const int b = bh >> 3, h = bh & 7;
    const u16* src = qkv + (long)(b * SEQ + st) * NQKV + 2 * EDIM + h * HDIM + dt;
#pragma unroll
    for (int p = 0; p < 2; ++p) {
      const int idx = p * 2048 + tid * 8;
      const int sr = idx >> 6, dc = idx & 63;
      const uint4 v = *(const uint4*)(src + (long)sr * NQKV + dc);
      const u16* pv = (const u16*)&v;
#pragma unroll
      for (int e = 0; e < 8; ++e) tile[sr][dc + e] = pv[e];
    }
    __syncthreads();
    u16* dst = vt + ((long)bh * HDIM + dt) * SEQ + st;
#pragma unroll
    for (int p = 0; p < 2; ++p) {
      const int idx = p * 2048 + tid * 8;
      const int dr = idx >> 6, sc = idx & 63;
      u16 tmp[8];
#pragma unroll
      for (int e = 0; e < 8; ++e) tmp[e] = tile[sc + e][dr];
      *(uint4*)(dst + (long)dr * SEQ + sc) = *(const uint4*)tmp;
    }
  }
}

// ---------------- flash attention v3 (r8-verified single-dispatch config) ------------
// 2-barrier loop + T5 setprio; 65.4us measured. (r9's bh-split doubled the
// critical path — two sequential dispatches each bounded by the 16-ktile blocks,
// +40us — reverted.)
__global__ void __launch_bounds__(256) flash_attn(const u16* __restrict__ qkv,
                                                  const u16* __restrict__ vt,
                                                  u16* __restrict__ opart,
                                                  float* __restrict__ lpart,
                                                  u16* __restrict__ ob) {
  const int bh = blockIdx.x, b = bh >> 3, h = bh & 7;
  const int qt = 31 - (int)blockIdx.y;
  const int kc = blockIdx.z;
  if (kc && qt < 16) return;
  const int kt0 = kc * 16;
  const int kt_end = (qt < kt0 + 15) ? qt : (kt0 + 15);

  __shared__ __align__(16) u16 Ks[64 * 256];
  __shared__ __align__(16) u16 Vs[256 * 64];
  __shared__ __align__(16) u16 Pb[4 * 16 * 64];
  const int tid = threadIdx.x;
  const int wave = tid >> 6, lane = tid & 63;
  const int quad = lane >> 4, l16 = lane & 15;
  const long qbase = (long)(b * SEQ + qt * 64) * NQKV + h * HDIM;
  const long kbase = (long)(b * SEQ) * NQKV + EDIM + h * HDIM;
  const long vbase = (long)bh * HDIM * SEQ;

#pragma unroll
  for (int p = 0; p < 8; ++p) {
    const int o = p * 4096 + tid * 16;
    const int row = o >> 9;
    const int cg = ((o >> 4) & 31) ^ (row & 7);
    gload16(qkv + qbase + (long)row * NQKV + cg * 8, (char*)Ks + o);
  }
  __syncthreads();
  bf16x8 qf[8];
  {
    const int qr = wave * 16 + l16;
#pragma unroll
    for (int ks = 0; ks < 8; ++ks) {
      const int u = ks * 4 + quad;
      qf[ks] = *(const bf16x8*)(Ks + qr * 256 + (u ^ (qr & 7)) * 8);
    }
  }
  __syncthreads();

#pragma unroll
  for (int p = 0; p < 8; ++p) {
    const int o = p * 4096 + tid * 16;
    const int row = o >> 9;
    const int cg = ((o >> 4) & 31) ^ (row & 7);
    gload16(qkv + kbase + (long)(kt0 * 64 + row) * NQKV + cg * 8, (char*)Ks + o);
  }

  const f32x4 fz = {0.f, 0.f, 0.f, 0.f};
  f32x4 O[16];
#pragma unroll
  for (int t = 0; t < 16; ++t) O[t] = fz;
  float lacc[4] = {0.f, 0.f, 0.f, 0.f};
  const float C1 = SCALE * LOG2E;
  const float C2 = 16.0f * LOG2E;

  for (int kt = kt0; kt <= kt_end; ++kt) {
    __syncthreads();
#pragma unroll
    for (int p = 0; p < 8; ++p) {
      const int o = p * 4096 + tid * 16;
      const int row = o >> 7;
      const int cg = ((o >> 4) & 7) ^ (row & 7);
      gload16(vt + vbase + (long)row * SEQ + kt * 64 + cg * 8, (char*)Vs + o);
    }
    f32x4 S[4];
#pragma unroll
    for (int nt = 0; nt < 4; ++nt) S[nt] = fz;
    __builtin_amdgcn_s_setprio(1);
#pragma unroll
    for (int nt = 0; nt < 4; ++nt) {
      const int kr = nt * 16 + l16;
#pragma unroll
      for (int ks = 0; ks < 8; ++ks) {
        const int u = ks * 4 + quad;
        const bf16x8 kf = *(const bf16x8*)(Ks + kr * 256 + (u ^ (kr & 7)) * 8);
        S[nt] = __builtin_amdgcn_mfma_f32_16x16x32_bf16(qf[ks], kf, S[nt], 0, 0, 0);
      }
    }
    __builtin_amdgcn_s_setprio(0);
    u16* Pw = Pb + wave * (16 * 64);
    if (kt == qt) {
      const int qg0 = qt * 64 + wave * 16 + quad * 4;
      const int kg0 = kt * 64 + l16;
#pragma unroll
      for (int nt = 0; nt < 4; ++nt) {
        const int kg = kg0 + nt * 16;
#pragma unroll
        for (int r = 0; r < 4; ++r) {
          float p = exp2f(S[nt][r] * C1 - C2);
          p = (kg <= qg0 + r) ? p : 0.f;
          lacc[r] += p;
          const int qrow = quad * 4 + r;
          const int col = nt * 16 + l16;
          Pw[qrow * 64 + (((col >> 3) ^ (qrow & 7)) * 8) + (col & 7)] = f2bf(p);
        }
      }
    } else {
#pragma unroll
      for (int nt = 0; nt < 4; ++nt) {
#pragma unroll
        for (int r = 0; r < 4; ++r) {
          const float p = exp2f(S[nt][r] * C1 - C2);
          lacc[r] += p;
          const int qrow = quad * 4 + r;
          const int col = nt * 16 + l16;
          Pw[qrow * 64 + (((col >> 3) ^ (qrow & 7)) * 8) + (col & 7)] = f2bf(p);
        }
      }
    }
    __syncthreads();
    if (kt < kt_end) {
#pragma unroll
      for (int p = 0; p < 8; ++p) {
        const int o = p * 4096 + tid * 16;
        const int row = o >> 9;
        const int cg = ((o >> 4) & 31) ^ (row & 7);
        gload16(qkv + kbase + (long)((kt + 1) * 64 + row) * NQKV + cg * 8, (char*)Ks + o);
      }
    }
    bf16x8 pf[2];
#pragma unroll
    for (int ks = 0; ks < 2; ++ks) {
      const int u = ks * 4 + quad;
      pf[ks] = *(const bf16x8*)(Pw + l16 * 64 + (u ^ (l16 & 7)) * 8);
    }
    __builtin_amdgcn_s_setprio(1);
#pragma unroll
    for (int nt = 0; nt < 16; ++nt) {
      const int vr = nt * 16 + l16;
#pragma unroll
      for (int ks = 0; ks < 2; ++ks) {
        const int u = ks * 4 + quad;
        const bf16x8 vf = *(const bf16x8*)(Vs + vr * 64 + (u ^ (vr & 7)) * 8);
        O[nt] = __builtin_amdgcn_mfma_f32_16x16x32_bf16(pf[ks], vf, O[nt], 0, 0, 0);
      }
    }
    __builtin_amdgcn_s_setprio(0);
  }
#pragma unroll
  for (int off = 1; off < 16; off <<= 1)
#pragma unroll
    for (int r = 0; r < 4; ++r) lacc[r] += __shfl_xor(lacc[r], off);

  if (qt < 16) {
    const float rv[4] = {1.0f / lacc[0], 1.0f / lacc[1], 1.0f / lacc[2], 1.0f / lacc[3]};
#pragma unroll
    for (int nt = 0; nt < 16; ++nt) {
      const int col = nt * 16 + l16;
#pragma unroll
      for (int r = 0; r < 4; ++r) {
        const int qrow = wave * 16 + quad * 4 + r;
        ob[((long)(b * SEQ + qt * 64 + qrow)) * EDIM + h * HDIM + col] =
            f2bf(O[nt][r] * rv[r]);
      }
    }
  } else {
    const long pbase = ((long)(bh * 32 + qt) * 2 + kc) * (64 * 256);
#pragma unroll
    for (int nt = 0; nt < 16; ++nt) {
      const int col = nt * 16 + l16;
#pragma unroll
      for (int r = 0; r < 4; ++r) {
        const int qrow = wave * 16 + quad * 4 + r;
        opart[pbase + (long)qrow * 256 + col] = f2bf(O[nt][r]);
      }
    }
    if (l16 == 0) {
      const long lbase = ((long)(bh * 32 + qt) * 2 + kc) * 64;
#pragma unroll
      for (int r = 0; r < 4; ++r)
        lpart[lbase + wave * 16 + quad * 4 + r] = lacc[r];
    }
  }
}

// ---------------- combine split-K partials (qt>=16 only) ----------------
__global__ void __launch_bounds__(256) fa_combine(const u16* __restrict__ opart,
                                                  const float* __restrict__ lpart,
                                                  u16* __restrict__ ob) {
  const int bh = blockIdx.x, qt = 16 + blockIdx.y;
  const int b = bh >> 3, h = bh & 7;
  const long p0 = ((long)(bh * 32 + qt) * 2) * (64 * 256);
  const long l0 = ((long)(bh * 32 + qt) * 2) * 64;
  __shared__ float rl[64];
  if (threadIdx.x < 64) {
    const float l = lpart[l0 + threadIdx.x] + lpart[l0 + 64 + threadIdx.x];
    rl[threadIdx.x] = 1.0f / l;
  }
  __syncthreads();
#pragma unroll
  for (int i = 0; i < 8; ++i) {
    const int e = i * 2048 + threadIdx.x * 8;
    const int row = e >> 8, d = e & 255;
    const u16* a = opart + p0 + e;
    const u16* c = a + 64 * 256;
    float v[8];
#pragma unroll
    for (int j = 0; j < 8; ++j) v[j] = bf2f(a[j]) + bf2f(c[j]);
    const float inv = rl[row];
    u16 o[8];
#pragma unroll
    for (int j = 0; j < 8; ++j) o[j] = f2bf(v[j] * inv);
    *(uint4*)(ob + ((long)(b * SEQ + qt * 64 + row)) * EDIM + h * HDIM + d) =
        *(const uint4*)o;
  }
}

// ---------------- launch ----------------
extern "C" void kernel_launch(void* const* d_in, const int* in_sizes, int n_in,
                              void* d_out, int out_size, void* d_ws, size_t ws_size,
                              hipStream_t stream) {
  const float* x  = (const float*)d_in[0];
  const int* pos  = (const int*)d_in[1];
  const float* Wq = (const float*)d_in[2];
  const float* Wk = (const float*)d_in[3];
  const float* Wv = (const float*)d_in[4];
  const float* Wo = (const float*)d_in[5];
  const float* qw = (const float*)d_in[6];
  const float* kw = (const float*)d_in[7];

  char* ws = (char*)d_ws;
  uint4* xbP   = (uint4*)(ws);               // 16 MiB  x packets [256][4096]  [dead after GEMM1]
  uint4* WcatP = (uint4*)(ws + 16777216L);   // 24 MiB  W packets [256][6144]  [dead after GEMM1]
  uint4* WobP  = (uint4*)(ws + 41943040L);   //  8 MiB  Wo packets [256][2048]
  u16* QKVb = (u16*)(ws + 50331648L);        // 48 MiB  qkv bf16 (4096x6144)
  u16* Vt   = (u16*)(ws + 100663296L);       // 16 MiB  V^T bf16 (16x256x2048)
  u16* Ob   = (u16*)(ws + 117440512L);       // 16 MiB  attn out bf16 (4096x2048)
  u16*   Opart = (u16*)(ws);                 // 32 MiB  overlay (dead xbP/WcatP region)
  float* Lpart = (float*)(ws + 33554432L);   // 256 KiB
  // RoPE table: 2 MiB, lives in the dead-xbP region AFTER gemm1 reads complete and is
  // dead again before flash's Opart overlay touches it (last read: norm_rope_tv).
  float4* Rtab = (float4*)(ws + 16777216L);  // overlays WcatP region (dead after gemm1)

  cast_pack<<<6144, 256, 0, stream>>>(x, Wq, Wk, Wv, Wo, xbP, WcatP, WobP);

  // QKV projection: single dispatch (r6-verified 112.5us config)
  gemm_pk128<<<dim3(32, 48), 256, 0, stream>>>(xbP, WcatP, QKVb, 4096, 6144, NQKV, DIMM);
  // build RoPE table after gemm1 (WcatP dead); 131072 entries
  rope_table<<<512, 256, 0, stream>>>(pos, Rtab);
  norm_rope_tv<<<18432, 256, 0, stream>>>(QKVb, Rtab, qw, kw, Vt);
  // flash attention: single dispatch (r8-verified 65.4us config)
  flash_attn<<<dim3(16, 32, 2), 256, 0, stream>>>(QKVb, Vt, Opart, Lpart, Ob);
  fa_combine<<<dim3(16, 16), 256, 0, stream>>>(Opart, Lpart, Ob);
  // output projection: mixed-operand kernel (A row-major swizzled, B packets), fp32 out
  gemm_mx128<<<dim3(32, 16), 256, 0, stream>>>(Ob, WobP, (float*)d_out, 2048, DIMM, EDIM);
}